// Round 1
// 3708.715 us; speedup vs baseline: 1.1832x; 1.1832x over previous
//
#include <hip/hip_runtime.h>
#include <hip/hip_bf16.h>
#include <math.h>

typedef __hip_bfloat16 bf16;
typedef __attribute__((ext_vector_type(8))) short bf16x8;
typedef __attribute__((ext_vector_type(4))) short bf16x4;
typedef __attribute__((ext_vector_type(4))) float f32x4;

constexpr int kN  = 346;     // nodes
constexpr int kL  = 50;      // seq len
constexpr int kD  = 300;     // emb dim
constexpr int kH  = 300;     // hidden
constexpr int kG  = 1200;    // 4*H
constexpr int kNL = kN * kL; // 17300
constexpr int kNLp = 17408;  // kNL padded to 128
constexpr int kNp  = 384;    // kN padded to 128
constexpr int kKp0 = 320;    // K=300 padded to 32
constexpr int kKp1 = 608;    // K=600 padded to 32
constexpr int kGp  = 1280;   // N=1200 padded to 128
constexpr int kHB  = 384;    // h-state rows padded

__device__ inline float toF(float v) { return v; }
__device__ inline float toF(bf16 v) { return __bfloat162float(v); }
__device__ inline void storeC(float* p, float v) { *p = v; }
__device__ inline void storeC(bf16* p, float v) { *p = __float2bfloat16(v); }
__device__ inline float sigf(float x) { return 1.f / (1.f + expf(-x)); }
__device__ inline float bfbits2f(unsigned short u) {
    unsigned int x = ((unsigned int)u) << 16;
    float f; __builtin_memcpy(&f, &x, 4); return f;
}
__device__ inline short f2bf_bits(float f) {
    bf16 b = __float2bfloat16(f);
    short s; __builtin_memcpy(&s, &b, 2); return s;
}

// ---------------------------------------------------------------------------
// MFMA GEMM: C(MxN) = A(MxK) @ B^T where A is (Mpad x lda) bf16 K-contiguous,
// B is (Npad x ldb) bf16 K-contiguous. K multiple of 32, pads zero-filled.
// EPI: 0 plain, 3 elu, 4 tanh
// ---------------------------------------------------------------------------
template <int EPI, typename CT>
__global__ __launch_bounds__(256) void gemm_mfma(
    const bf16* __restrict__ A, const bf16* __restrict__ B, CT* __restrict__ C,
    int M, int N, int K, int lda, int ldb, int ldc,
    long sAz, long sBz, long sCz,
    const bf16* __restrict__ P, long sPz, const float* __restrict__ bias, long sbz)
{
    const short* Ag = (const short*)A + (size_t)blockIdx.z * sAz;
    const short* Bg = (const short*)B + (size_t)blockIdx.z * sBz;
    CT* Cg = C + (size_t)blockIdx.z * sCz;
    (void)P; (void)sPz; (void)bias; (void)sbz;

    __shared__ short As[128 * 40];   // row stride 40 (80B) -> 2-way aliasing (free)
    __shared__ short Bs[128 * 40];
    int tid = threadIdx.x;
    int row0 = blockIdx.y * 128, col0 = blockIdx.x * 128;
    int wave = tid >> 6, lane = tid & 63;
    int wr = (wave >> 1) * 64, wc = (wave & 1) * 64;
    int lrow = lane & 15, lq = lane >> 4;

    f32x4 acc[4][4];
#pragma unroll
    for (int i = 0; i < 4; ++i)
#pragma unroll
        for (int j = 0; j < 4; ++j) acc[i][j] = (f32x4){0.f, 0.f, 0.f, 0.f};

    int sr = tid >> 2;
    int sc = (tid & 3) * 8;
    for (int k0 = 0; k0 < K; k0 += 32) {
        *(bf16x8*)&As[sr * 40 + sc]        = *(const bf16x8*)&Ag[(size_t)(row0 + sr) * lda + k0 + sc];
        *(bf16x8*)&As[(sr + 64) * 40 + sc] = *(const bf16x8*)&Ag[(size_t)(row0 + sr + 64) * lda + k0 + sc];
        *(bf16x8*)&Bs[sr * 40 + sc]        = *(const bf16x8*)&Bg[(size_t)(col0 + sr) * ldb + k0 + sc];
        *(bf16x8*)&Bs[(sr + 64) * 40 + sc] = *(const bf16x8*)&Bg[(size_t)(col0 + sr + 64) * ldb + k0 + sc];
        __syncthreads();
        bf16x8 aF[4], bF[4];
#pragma unroll
        for (int i = 0; i < 4; ++i) aF[i] = *(const bf16x8*)&As[(wr + i * 16 + lrow) * 40 + lq * 8];
#pragma unroll
        for (int j = 0; j < 4; ++j) bF[j] = *(const bf16x8*)&Bs[(wc + j * 16 + lrow) * 40 + lq * 8];
#pragma unroll
        for (int i = 0; i < 4; ++i)
#pragma unroll
            for (int j = 0; j < 4; ++j)
                acc[i][j] = __builtin_amdgcn_mfma_f32_16x16x32_bf16(aF[i], bF[j], acc[i][j], 0, 0, 0);
        __syncthreads();
    }
#pragma unroll
    for (int i = 0; i < 4; ++i) {
#pragma unroll
        for (int r = 0; r < 4; ++r) {
            int gm = row0 + wr + i * 16 + lq * 4 + r;
            if (gm >= M) continue;
#pragma unroll
            for (int j = 0; j < 4; ++j) {
                int gn = col0 + wc + j * 16 + lrow;
                if (gn >= N) continue;
                float v = acc[i][j][r];
                if constexpr (EPI == 3) v = v > 0.f ? v : (expf(v) - 1.f);
                if constexpr (EPI == 4) v = tanhf(v);
                storeC(&Cg[(size_t)gm * ldc + gn], v);
            }
        }
    }
}

// fp32 (R x Cc) row-major -> bf16 (Cpad x Rpad) transposed, zero-padded
__global__ void transpose_conv(const float* __restrict__ in, bf16* __restrict__ out,
                               int R, int Cc, int Rpad, int Cpad) {
    __shared__ float tile[32][33];
    int bc = blockIdx.x * 32, br = blockIdx.y * 32;
    int tx = threadIdx.x & 31, ty = threadIdx.x >> 5;
#pragma unroll
    for (int k = 0; k < 4; ++k) {
        int r = br + ty + 8 * k, c = bc + tx;
        tile[ty + 8 * k][tx] = (r < R && c < Cc) ? in[(size_t)r * Cc + c] : 0.f;
    }
    __syncthreads();
#pragma unroll
    for (int k = 0; k < 4; ++k) {
        int c = bc + ty + 8 * k, r = br + tx;
        if (c < Cpad && r < Rpad) out[(size_t)c * Rpad + r] = __float2bfloat16(tile[tx][ty + 8 * k]);
    }
}

// LSTM weight convert: rows permuted gate-interleaved: out row rp = j*4+q holds
// in row q*300+j. Out (1280 x Cpad) bf16, zero pads.
__global__ void convert_pad_perm(const float* __restrict__ in, bf16* __restrict__ out,
                                 int Cc, int Cpad) {
    int idx = blockIdx.x * 256 + threadIdx.x;
    if (idx >= kGp * Cpad) return;
    int rp = idx / Cpad, c = idx - rp * Cpad;
    int j = rp >> 2, q = rp & 3;
    float v = (j < kH && c < Cc) ? in[(size_t)(q * kH + j) * Cc + c] : 0.f;
    out[idx] = __float2bfloat16(v);
}

// permuted biases: b[dir][1280], b'[j*4+q] = b_orig[q*300+j], zero pads
__global__ void pack_biases_perm(const float* b0f, const float* b0b, const float* b1f,
                                 const float* b1b, float* b0, float* b1) {
    int i = blockIdx.x * 256 + threadIdx.x;
    if (i >= 2 * kGp) return;
    int dir = i / kGp, rp = i - dir * kGp;
    int j = rp >> 2, q = rp & 3;
    float v0 = 0.f, v1 = 0.f;
    if (j < kH) {
        v0 = dir ? b0b[q * kH + j] : b0f[q * kH + j];
        v1 = dir ? b1b[q * kH + j] : b1f[q * kH + j];
    }
    b0[i] = v0; b1[i] = v1;
}

// embedding gather -> xPad (kNLp x kKp0) bf16, zero pads
__global__ void gather_kernel(const int* __restrict__ tokens, const float* __restrict__ emb,
                              bf16* __restrict__ x) {
    int idx = blockIdx.x * 256 + threadIdx.x;
    if (idx >= kNLp * kKp0) return;
    int row = idx / kKp0, d = idx - row * kKp0;
    float v = 0.f;
    if (row < kNL && d < kD) {
        int l = row / kN, n = row - l * kN;
        v = emb[(size_t)tokens[n * kL + l] * kD + d];
    }
    x[idx] = __float2bfloat16(v);
}

// ---------------------------------------------------------------------------
// Persistent fused LSTM scan (one launch per layer).
// Grid = 60 blocks: cb(0..9) x rb(0..2) x dir(0..1), 1 block/CU.
// Gate-interleaved Whh (col' = j*4+q) so each 128-col tile = 32 hidden x 4
// gates -> pointwise update is block-local. Whh tile LDS-resident (swizzled);
// h ping-pong bf16 in global; c fp32 in registers; 10-block group barrier per
// step (readers/writers of h rows (rb,dir) are exactly the 10 cb blocks).
// ---------------------------------------------------------------------------
__device__ inline void group_barrier(int* bar, int target) {
    __syncthreads();                 // all waves' vmem drained (compiler waitcnt)
    if (threadIdx.x == 0) {
        __threadfence();             // release: L2 writeback to coherence point
        __hip_atomic_fetch_add(bar, 1, __ATOMIC_RELAXED, __HIP_MEMORY_SCOPE_AGENT);
        while (__hip_atomic_load(bar, __ATOMIC_RELAXED, __HIP_MEMORY_SCOPE_AGENT) < target)
            __builtin_amdgcn_s_sleep(2);
    }
    __syncthreads();
    __threadfence();                 // acquire: invalidate L1/L2
}

template <bool WRITE_O0>
__global__ __launch_bounds__(256, 1) void lstm_scan_fused(
    const bf16* __restrict__ WhhP,   // [2][1280][320] bf16, gate-interleaved rows
    const bf16* __restrict__ P,      // [2][kNL][1200] bf16, gate-interleaved cols
    const float* __restrict__ biasP, // [2][1280] f32, gate-interleaved
    bf16* __restrict__ hst,          // [2 buf][2 dir][384][320] bf16, zeroed
    bf16* __restrict__ o0,           // [kNLp][608] bf16 (layer-0 only)
    int* __restrict__ bars)          // [6] ints, zeroed
{
    __shared__ short Bs[10][128][32];        // 80 KiB, k-group XOR-swizzled
    __shared__ float Gs[4 * 32 * 128];       // 64 KiB, row XOR-swizzled

    const int tid = threadIdx.x;
    const int bx  = blockIdx.x;
    const int cb  = bx % 10;
    const int rb  = (bx / 10) % 3;
    const int dir = bx / 30;
    int* bar = bars + dir * 3 + rb;

    const int wave = tid >> 6, lane = tid & 63;
    const int wr = (wave >> 1) * 64, wc = (wave & 1) * 64;
    const int lrow = lane & 15, lq = lane >> 4;
    const int col0 = cb * 128, row0 = rb * 128;

    // ---- stage Whh tile -> LDS once (swizzle: k-group g stored at g^((row>>1)&3)) ----
    {
        const short* Bg = (const short*)WhhP + (size_t)dir * kGp * kKp0;
        int sr = tid >> 2;           // 0..63
        int g  = tid & 3;            // k-group within 32-chunk
#pragma unroll
        for (int ch = 0; ch < 10; ++ch) {
            *(bf16x8*)&Bs[ch][sr][(g ^ ((sr >> 1) & 3)) * 8] =
                *(const bf16x8*)&Bg[(size_t)(col0 + sr) * kKp0 + ch * 32 + g * 8];
            *(bf16x8*)&Bs[ch][sr + 64][(g ^ (((sr + 64) >> 1) & 3)) * 8] =
                *(const bf16x8*)&Bg[(size_t)(col0 + sr + 64) * kKp0 + ch * 32 + g * 8];
        }
    }

    // pointwise assignment: thread owns 4 rows x 4 hidden units
    const int jj0 = (tid >> 5) * 4;       // local hidden base 0..28
    const int pr0 = (tid & 31) * 4;       // local row base 0..124
    const int jg0 = cb * 32 + jj0;        // global hidden base (mult of 4; 300%4==0)
    const bool jok = jg0 < kH;

    float bias[4][4];                     // [m][q]
#pragma unroll
    for (int m = 0; m < 4; ++m) {
        f32x4 b4 = *(const f32x4*)&biasP[dir * kGp + col0 + (jj0 + m) * 4];
#pragma unroll
        for (int q = 0; q < 4; ++q) bias[m][q] = b4[q];
    }
    float cst[4][4];                      // [m][rr] fp32 cell state
#pragma unroll
    for (int m = 0; m < 4; ++m)
#pragma unroll
        for (int r = 0; r < 4; ++r) cst[m][r] = 0.f;

    short* o0s = (short*)o0;
    __syncthreads();

#pragma unroll 1
    for (int t = 0; t < kL; ++t) {
        const short* hr = (const short*)hst + ((size_t)(t & 1) * 2 + dir) * (kHB * kKp0);
        short* hw = (short*)hst + ((size_t)((t + 1) & 1) * 2 + dir) * (kHB * kKp0);
        const int teff = dir ? (kL - 1 - t) : t;
        const short* Pt = (const short*)P + (size_t)dir * kNL * kG + (size_t)teff * kN * kG;

        // prefetch P[t] for this thread's pointwise slots (hides L3 latency)
        bf16x4 pv[4][4];                  // [m][rr]
        if (jok) {
#pragma unroll
            for (int m = 0; m < 4; ++m)
#pragma unroll
                for (int rr = 0; rr < 4; ++rr) {
                    int rg = row0 + pr0 + rr;
                    if (rg < kN)
                        pv[m][rr] = *(const bf16x4*)&Pt[(size_t)rg * kG + (size_t)(jg0 + m) * 4];
                }
        }

        // ---- GEMM: g += h_prev @ WhhP^T (A from global/L2, B from LDS) ----
        f32x4 acc[4][4];
#pragma unroll
        for (int i = 0; i < 4; ++i)
#pragma unroll
            for (int j = 0; j < 4; ++j) acc[i][j] = (f32x4){0.f, 0.f, 0.f, 0.f};

#pragma unroll
        for (int ch = 0; ch < 10; ++ch) {
            bf16x8 aF[4], bF[4];
#pragma unroll
            for (int i = 0; i < 4; ++i)
                aF[i] = *(const bf16x8*)&hr[(size_t)(row0 + wr + i * 16 + lrow) * kKp0 + ch * 32 + lq * 8];
#pragma unroll
            for (int j = 0; j < 4; ++j) {
                int brow = wc + j * 16 + lrow;
                bF[j] = *(const bf16x8*)&Bs[ch][brow][(lq ^ ((brow >> 1) & 3)) * 8];
            }
#pragma unroll
            for (int i = 0; i < 4; ++i)
#pragma unroll
                for (int j = 0; j < 4; ++j)
                    acc[i][j] = __builtin_amdgcn_mfma_f32_16x16x32_bf16(aF[i], bF[j], acc[i][j], 0, 0, 0);
        }

        // ---- acc -> Gs (re-shard MFMA layout -> pointwise layout) ----
#pragma unroll
        for (int i = 0; i < 4; ++i) {
            int r0 = wr + i * 16 + lq * 4;
#pragma unroll
            for (int j = 0; j < 4; ++j) {
                int c = wc + j * 16 + lrow;
                int q = c & 3, jj = c >> 2;
                *(f32x4*)&Gs[(q * 32 + jj) * 128 + (r0 ^ ((jj & 7) << 2))] = acc[i][j];
            }
        }
        __syncthreads();

        // ---- pointwise LSTM update ----
        if (jok) {
            float hval[4][4];             // [rr][m]
#pragma unroll
            for (int m = 0; m < 4; ++m) {
                int jjl = jj0 + m;
                int sw = (jjl & 7) << 2;
                f32x4 gi4 = *(const f32x4*)&Gs[(0 * 32 + jjl) * 128 + (pr0 ^ sw)];
                f32x4 gf4 = *(const f32x4*)&Gs[(1 * 32 + jjl) * 128 + (pr0 ^ sw)];
                f32x4 gg4 = *(const f32x4*)&Gs[(2 * 32 + jjl) * 128 + (pr0 ^ sw)];
                f32x4 go4 = *(const f32x4*)&Gs[(3 * 32 + jjl) * 128 + (pr0 ^ sw)];
#pragma unroll
                for (int rr = 0; rr < 4; ++rr) {
                    int rg = row0 + pr0 + rr;
                    if (rg >= kN) continue;
                    float iv = sigf(gi4[rr] + bfbits2f((unsigned short)pv[m][rr][0]) + bias[m][0]);
                    float fv = sigf(gf4[rr] + bfbits2f((unsigned short)pv[m][rr][1]) + bias[m][1]);
                    float gv = tanhf(gg4[rr] + bfbits2f((unsigned short)pv[m][rr][2]) + bias[m][2]);
                    float ov = sigf(go4[rr] + bfbits2f((unsigned short)pv[m][rr][3]) + bias[m][3]);
                    float cc = fv * cst[m][rr] + iv * gv;
                    cst[m][rr] = cc;
                    hval[rr][m] = ov * tanhf(cc);
                }
            }
#pragma unroll
            for (int rr = 0; rr < 4; ++rr) {
                int rg = row0 + pr0 + rr;
                if (rg >= kN) continue;
                bf16x4 hv;
#pragma unroll
                for (int m = 0; m < 4; ++m) hv[m] = f2bf_bits(hval[rr][m]);
                *(bf16x4*)&hw[(size_t)rg * kKp0 + jg0] = hv;
                if constexpr (WRITE_O0)
                    *(bf16x4*)&o0s[((size_t)teff * kN + rg) * kKp1 + dir * kH + jg0] = hv;
            }
        }

        group_barrier(bar, 10 * (t + 1));
    }
}

__global__ void concat_hs0(const bf16* __restrict__ hbf0, const bf16* __restrict__ hbf1,
                           float* __restrict__ hs0) {
    int idx = blockIdx.x * 256 + threadIdx.x;
    if (idx >= kN * kG) return;
    int r = idx / kG, c = idx - r * kG;
    float v;
    if (c < 300)       v = toF(hbf0[(size_t)r * kKp0 + c]);
    else if (c < 600)  v = toF(hbf0[(size_t)(kNp + r) * kKp0 + (c - 300)]);
    else if (c < 900)  v = toF(hbf1[(size_t)r * kKp0 + (c - 600)]);
    else               v = toF(hbf1[(size_t)(kNp + r) * kKp0 + (c - 900)]);
    hs0[idx] = v;
}

__global__ void colsum_kernel(const float* __restrict__ hs, float* __restrict__ sum_hx) {
    int c = blockIdx.x * 256 + threadIdx.x;
    if (c >= kG) return;
    float s = 0.f;
    for (int r = 1; r < kN; ++r) s += hs[(size_t)r * kG + c];
    sum_hx[c] = s;
}

__global__ void gate_rows(const float* __restrict__ hs, const float* __restrict__ gW,
                          const float* __restrict__ gU, const float* __restrict__ sum_hx,
                          bf16* __restrict__ hin) {
    __shared__ float red[256];
    int n = blockIdx.x, tid = threadIdx.x;
    for (int c = tid; c < kG; c += 256)
        hin[(size_t)n * 2400 + c] = __float2bfloat16(hs[(size_t)n * kG + c]);
    if (n == 0) {
        for (int c = tid; c < kG; c += 256)
            hin[1200 + c] = __float2bfloat16(hs[c]);
        return;
    }
    float dw = 0.f, du = 0.f;
    for (int c = tid; c < kG; c += 256) {
        dw += hs[(size_t)n * kG + c] * gW[c];
        du += hs[c] * gU[c];
    }
    red[tid] = dw; __syncthreads();
    for (int s = 128; s > 0; s >>= 1) { if (tid < s) red[tid] += red[tid + s]; __syncthreads(); }
    float sdw = red[0]; __syncthreads();
    red[tid] = du; __syncthreads();
    for (int s = 128; s > 0; s >>= 1) { if (tid < s) red[tid] += red[tid + s]; __syncthreads(); }
    float sdu = red[0]; __syncthreads();
    float gval = sigf(sdw + sdu);
    for (int c = tid; c < kG; c += 256) {
        float v = gval * sum_hx[c] + (1.f - gval) * (345.f * hs[c]);
        hin[(size_t)n * 2400 + 1200 + c] = __float2bfloat16(v);
    }
}

__global__ void gat_scores(const float* __restrict__ Wh, const float* __restrict__ a,
                           float* __restrict__ s1, float* __restrict__ s2) {
    __shared__ float red[256];
    int n = blockIdx.x, tid = threadIdx.x;
    float d1 = 0.f, d2 = 0.f;
    for (int c = tid; c < kG; c += 256) {
        float w = Wh[(size_t)n * kG + c];
        d1 += w * a[c];
        d2 += w * a[kG + c];
    }
    red[tid] = d1; __syncthreads();
    for (int s = 128; s > 0; s >>= 1) { if (tid < s) red[tid] += red[tid + s]; __syncthreads(); }
    if (tid == 0) s1[n] = red[0];
    __syncthreads();
    red[tid] = d2; __syncthreads();
    for (int s = 128; s > 0; s >>= 1) { if (tid < s) red[tid] += red[tid + s]; __syncthreads(); }
    if (tid == 0) s2[n] = red[0];
}

__global__ void gat_softmax(const float* __restrict__ s1, const float* __restrict__ s2,
                            const int* __restrict__ adj, bf16* __restrict__ att) {
    __shared__ float red[256];
    __shared__ float sh_m, sh_s;
    int i = blockIdx.x, tid = threadIdx.x;
    float s1i = s1[i];
    float m = -1e30f;
    for (int j = tid; j < kN; j += 256) {
        if (adj[i * kN + j] > 0) {
            float e = s1i + s2[j];
            e = e > 0.f ? e : 0.01f * e;
            m = fmaxf(m, e);
        }
    }
    red[tid] = m; __syncthreads();
    for (int s = 128; s > 0; s >>= 1) { if (tid < s) red[tid] = fmaxf(red[tid], red[tid + s]); __syncthreads(); }
    if (tid == 0) sh_m = red[0];
    __syncthreads();
    m = sh_m;
    float sum = 0.f;
    for (int j = tid; j < kN; j += 256) {
        if (adj[i * kN + j] > 0) {
            float e = s1i + s2[j];
            e = e > 0.f ? e : 0.01f * e;
            sum += expf(e - m);
        }
    }
    red[tid] = sum; __syncthreads();
    for (int s = 128; s > 0; s >>= 1) { if (tid < s) red[tid] += red[tid + s]; __syncthreads(); }
    if (tid == 0) sh_s = red[0];
    __syncthreads();
    float inv = sh_s > 0.f ? 1.f / sh_s : 0.f;
    for (int j = tid; j < kN; j += 256) {
        float v = 0.f;
        if (adj[i * kN + j] > 0) {
            float e = s1i + s2[j];
            e = e > 0.f ? e : 0.01f * e;
            v = expf(e - m) * inv;
        }
        att[(size_t)i * 352 + j] = __float2bfloat16(v);
    }
}

__global__ void build_cat4(const float* __restrict__ hs2, bf16* __restrict__ cat4) {
    int idx = blockIdx.x * 256 + threadIdx.x;
    if (idx >= kN * 4800) return;
    int r = idx / 4800, c = idx - r * 4800;
    int chunk = c / kG, cc = c - chunk * kG;
    float hc = hs2[cc];
    float hv = hs2[(size_t)r * kG + cc];
    float v = (chunk == 0) ? hc : (chunk == 1) ? hv : (chunk == 2) ? hc * hv : (hc - hv);
    cat4[idx] = __float2bfloat16(v);
}

__global__ void row_dot_tanh(const float* __restrict__ hc3, const float* __restrict__ FC2,
                             float* __restrict__ b_att) {
    __shared__ float red[256];
    int n = blockIdx.x, tid = threadIdx.x;
    float d = 0.f;
    for (int c = tid; c < 9600; c += 256) d += hc3[(size_t)n * 9600 + c] * FC2[c];
    red[tid] = d; __syncthreads();
    for (int s = 128; s > 0; s >>= 1) { if (tid < s) red[tid] += red[tid + s]; __syncthreads(); }
    if (tid == 0) b_att[n] = tanhf(red[0]);
}

__global__ void ea_kernel(const float* __restrict__ hs2, const float* __restrict__ b_att,
                          float* __restrict__ ea) {
    int c = blockIdx.x * 256 + threadIdx.x;
    if (c >= kG) return;
    float s = 0.f, w = 0.f;
    for (int r = 0; r < kN; ++r) {
        float v = hs2[(size_t)r * kG + c];
        s += v;
        w += b_att[r] * v;
    }
    ea[c] = s / (float)kN;
    ea[kG + c] = w;
}

__global__ void final_kernel(const float* __restrict__ ea, const float* __restrict__ Wlin,
                             const float* __restrict__ blin, float* __restrict__ out) {
    __shared__ float red[256];
    int tid = threadIdx.x;
    float l0 = 0.f, l1 = 0.f;
    for (int c = tid; c < 2400; c += 256) {
        float e = ea[c];
        l0 += e * Wlin[c];
        l1 += e * Wlin[2400 + c];
    }
    red[tid] = l0; __syncthreads();
    for (int s = 128; s > 0; s >>= 1) { if (tid < s) red[tid] += red[tid + s]; __syncthreads(); }
    l0 = red[0]; __syncthreads();
    red[tid] = l1; __syncthreads();
    for (int s = 128; s > 0; s >>= 1) { if (tid < s) red[tid] += red[tid + s]; __syncthreads(); }
    l1 = red[0];
    if (tid == 0) {
        l0 += blin[0];
        l1 += blin[1];
        float m = fmaxf(l0, l1);
        float e0 = expf(l0 - m), e1 = expf(l1 - m);
        float inv = 1.f / (e0 + e1);
        out[0] = e0 * inv;
        out[1] = e1 * inv;
    }
}

// ---------------------------------------------------------------------------
extern "C" void kernel_launch(void* const* d_in, const int* in_sizes, int n_in,
                              void* d_out, int out_size, void* d_ws, size_t ws_size,
                              hipStream_t stream) {
    const int*   tokens  = (const int*)d_in[0];
    const int*   adj     = (const int*)d_in[1];
    const float* emb     = (const float*)d_in[2];
    const float* Wih_l0f = (const float*)d_in[3];
    const float* Whh_l0f = (const float*)d_in[4];
    const float* b_l0f   = (const float*)d_in[5];
    const float* Wih_l0b = (const float*)d_in[6];
    const float* Whh_l0b = (const float*)d_in[7];
    const float* b_l0b   = (const float*)d_in[8];
    const float* Wih_l1f = (const float*)d_in[9];
    const float* Whh_l1f = (const float*)d_in[10];
    const float* b_l1f   = (const float*)d_in[11];
    const float* Wih_l1b = (const float*)d_in[12];
    const float* Whh_l1b = (const float*)d_in[13];
    const float* b_l1b   = (const float*)d_in[14];
    const float* W_gat   = (const float*)d_in[15];
    const float* a_gat   = (const float*)d_in[16];
    const float* gate_W  = (const float*)d_in[17];
    const float* gate_U  = (const float*)d_in[18];
    const float* FC1     = (const float*)d_in[19];
    const float* FC2     = (const float*)d_in[20];
    const float* Wlin    = (const float*)d_in[21];
    const float* blin    = (const float*)d_in[22];
    float* out = (float*)d_out;
    (void)in_sizes; (void)n_in; (void)out_size; (void)ws_size;

    char* base = (char*)d_ws;
    size_t off = 0;
    auto alloc = [&](size_t bytes) {
        size_t cur = off;
        off += (bytes + 255) & ~(size_t)255;
        return base + cur;
    };

    // Region A with phase overlays:
    //   phase 1: [xPad 11.1MB | P0 83MB]
    //   phase 2: [P1 83MB] (x,P0 dead)
    //   phase 3: [WgatT 6.1 | hin 1.8 | att 0.27] (P1 dead)
    //   phase 4: [FC1T 92.2MB] (GAT scratch dead)
    const size_t xPad_sz = (size_t)kNLp * kKp0 * 2;
    char* regA = alloc(94181120);
    bf16* xPad  = (bf16*)(regA);
    bf16* P0    = (bf16*)(regA + xPad_sz);
    bf16* P1    = (bf16*)(regA);
    bf16* WgatT = (bf16*)(regA);
    bf16* hin   = (bf16*)(regA + 6144000);
    bf16* att   = (bf16*)(regA + 7987200);
    bf16* FC1T  = (bf16*)(regA);
    const size_t gatScratch_sz = 8257536;

    // o0 region, later overlaid by hc3
    char* o0r   = alloc((size_t)kNLp * kKp1 * 2);
    bf16*  o0   = (bf16*)o0r;
    float* hc3  = (float*)o0r;

    // h-state ping-pong buffers (layer0, layer1) + group barriers; zeroed each call
    const size_t hst_sz = (size_t)2 * 2 * kHB * kKp0 * 2;   // 983,040
    char* hblk = alloc(hst_sz * 2 + 256);
    bf16* hstA = (bf16*)hblk;
    bf16* hstB = (bf16*)(hblk + hst_sz);
    int*  bars = (int*)(hblk + 2 * hst_sz);

    bf16* Wih0 = (bf16*)alloc((size_t)2 * kGp * kKp0 * 2);
    bf16* Wih1 = (bf16*)alloc((size_t)2 * kGp * kKp1 * 2);
    bf16* Whh0 = (bf16*)alloc((size_t)2 * kGp * kKp0 * 2);
    bf16* Whh1 = (bf16*)alloc((size_t)2 * kGp * kKp0 * 2);
    float* b0p = (float*)alloc(2 * kGp * 4);
    float* b1p = (float*)alloc(2 * kGp * 4);
    float* hsA = (float*)alloc((size_t)kN * kG * 4);
    float* hsB = (float*)alloc((size_t)kN * kG * 4);
    float* sum_hx = (float*)alloc(kG * 4);
    float* Wh  = (float*)alloc((size_t)kN * kG * 4);
    bf16*  WhT = (bf16*)alloc((size_t)kGp * 352 * 2);
    float* s1  = (float*)alloc(kN * 4);
    float* s2  = (float*)alloc(kN * 4);
    bf16*  cat4 = (bf16*)alloc((size_t)kNp * 4800 * 2);
    float* b_att = (float*)alloc(kN * 4);
    float* ea  = (float*)alloc(2400 * 4);

    // ---- init (ws is re-poisoned every call) ----
    hipMemsetAsync(hblk, 0, hst_sz * 2 + 256, stream);
    hipMemsetAsync(o0r, 0, (size_t)kNLp * kKp1 * 2, stream);
    hipMemsetAsync(cat4, 0, (size_t)kNp * 4800 * 2, stream);

    // ---- weight prep (gate-interleaved permutation for all LSTM weights) ----
    pack_biases_perm<<<10, 256, 0, stream>>>(b_l0f, b_l0b, b_l1f, b_l1b, b0p, b1p);
    int cpp0 = (kGp * kKp0 + 255) / 256;
    int cpp1 = (kGp * kKp1 + 255) / 256;
    convert_pad_perm<<<cpp0, 256, 0, stream>>>(Wih_l0f, Wih0,              kD,     kKp0);
    convert_pad_perm<<<cpp0, 256, 0, stream>>>(Wih_l0b, Wih0 + kGp * kKp0, kD,     kKp0);
    convert_pad_perm<<<cpp1, 256, 0, stream>>>(Wih_l1f, Wih1,              2 * kH, kKp1);
    convert_pad_perm<<<cpp1, 256, 0, stream>>>(Wih_l1b, Wih1 + kGp * kKp1, 2 * kH, kKp1);
    convert_pad_perm<<<cpp0, 256, 0, stream>>>(Whh_l0f, Whh0,              kH,     kKp0);
    convert_pad_perm<<<cpp0, 256, 0, stream>>>(Whh_l0b, Whh0 + kGp * kKp0, kH,     kKp0);
    convert_pad_perm<<<cpp0, 256, 0, stream>>>(Whh_l1f, Whh1,              kH,     kKp0);
    convert_pad_perm<<<cpp0, 256, 0, stream>>>(Whh_l1b, Whh1 + kGp * kKp0, kH,     kKp0);

    // ---- embedding gather ----
    gather_kernel<<<(kNLp * kKp0 + 255) / 256, 256, 0, stream>>>(tokens, emb, xPad);

    // ---- layer-0 input projections (z=dir), gate-interleaved P columns ----
    gemm_mfma<0, bf16><<<dim3(10, kNLp / 128, 2), 256, 0, stream>>>(
        xPad, Wih0, P0, kNL, kG, kKp0, kKp0, kKp0, kG,
        0, (long)kGp * kKp0, (long)kNL * kG, nullptr, 0, nullptr, 0);

    // ---- layer-0 scan: ONE persistent kernel (was 100 launches) ----
    lstm_scan_fused<true><<<60, 256, 0, stream>>>(Whh0, P0, b0p, hstA, o0, bars);

    // ---- layer-1 input projections (P1 overlays dead xPad/P0) ----
    gemm_mfma<0, bf16><<<dim3(10, kNLp / 128, 2), 256, 0, stream>>>(
        o0, Wih1, P1, kNL, kG, kKp1, kKp1, kKp1, kG,
        0, (long)kGp * kKp1, (long)kNL * kG, nullptr, 0, nullptr, 0);

    // ---- layer-1 scan ----
    lstm_scan_fused<false><<<60, 256, 0, stream>>>(Whh1, P1, b1p, hstB, nullptr, bars + 6);

    // ---- hs0 = [hf0, hb0, hf1, hb1] (final h lives in buf0 of each state) ----
    concat_hs0<<<(kN * kG + 255) / 256, 256, 0, stream>>>(hstA, hstB, hsA);

    // ---- GAT scratch (overlays dead P1); zero pads then fill WgatT ----
    hipMemsetAsync(regA, 0, gatScratch_sz, stream);
    transpose_conv<<<dim3(kGp / 32, 2400 / 32), 256, 0, stream>>>(W_gat, WgatT, 2400, kG, 2400, kGp);

    float* hsIn = hsA;
    float* hsOut = hsB;
    for (int it = 0; it < 2; ++it) {
        colsum_kernel<<<(kG + 255) / 256, 256, 0, stream>>>(hsIn, sum_hx);
        gate_rows<<<kN, 256, 0, stream>>>(hsIn, gate_W, gate_U, sum_hx, hin);
        gemm_mfma<0, float><<<dim3(10, 3, 1), 256, 0, stream>>>(
            hin, WgatT, Wh, kN, kG, 2400, 2400, 2400, kG,
            0, 0, 0, nullptr, 0, nullptr, 0);
        gat_scores<<<kN, 256, 0, stream>>>(Wh, a_gat, s1, s2);
        gat_softmax<<<kN, 256, 0, stream>>>(s1, s2, adj, att);
        transpose_conv<<<dim3(kGp / 32, 352 / 32), 256, 0, stream>>>(Wh, WhT, kN, kG, 352, kGp);
        gemm_mfma<3, float><<<dim3(10, 3, 1), 256, 0, stream>>>(
            att, WhT, hsOut, kN, kG, 352, 352, 352, kG,
            0, 0, 0, nullptr, 0, nullptr, 0);
        float* tmp = hsIn; hsIn = hsOut; hsOut = tmp;
    }

    // ---- head ----
    build_cat4<<<(kN * 4800 + 255) / 256, 256, 0, stream>>>(hsIn, cat4);
    transpose_conv<<<dim3(9600 / 32, 4800 / 32), 256, 0, stream>>>(FC1, FC1T, 4800, 9600, 4800, 9600);
    gemm_mfma<4, float><<<dim3(75, 3, 1), 256, 0, stream>>>(
        cat4, FC1T, hc3, kN, 9600, 4800, 4800, 4800, 9600,
        0, 0, 0, nullptr, 0, nullptr, 0);
    row_dot_tanh<<<kN, 256, 0, stream>>>(hc3, FC2, b_att);
    ea_kernel<<<(kG + 255) / 256, 256, 0, stream>>>(hsIn, b_att, ea);
    final_kernel<<<1, 256, 0, stream>>>(ea, Wlin, blin, out);
}

// Round 2
// 3650.860 us; speedup vs baseline: 1.2020x; 1.0158x over previous
//
#include <hip/hip_runtime.h>
#include <hip/hip_bf16.h>
#include <math.h>

typedef __hip_bfloat16 bf16;
typedef __attribute__((ext_vector_type(8))) short bf16x8;
typedef __attribute__((ext_vector_type(4))) short bf16x4;
typedef __attribute__((ext_vector_type(4))) float f32x4;

constexpr int kN  = 346;     // nodes
constexpr int kL  = 50;      // seq len
constexpr int kD  = 300;     // emb dim
constexpr int kH  = 300;     // hidden
constexpr int kG  = 1200;    // 4*H
constexpr int kNL = kN * kL; // 17300
constexpr int kNLp = 17408;  // kNL padded to 128
constexpr int kNp  = 384;    // kN padded to 128
constexpr int kKp0 = 320;    // K=300 padded to 32
constexpr int kKp1 = 608;    // K=600 padded to 32
constexpr int kGp  = 1280;   // N=1200 padded to 128
constexpr int kHB  = 384;    // h-state rows padded

__device__ inline float toF(float v) { return v; }
__device__ inline float toF(bf16 v) { return __bfloat162float(v); }
__device__ inline void storeC(float* p, float v) { *p = v; }
__device__ inline void storeC(bf16* p, float v) { *p = __float2bfloat16(v); }
__device__ inline float sigf(float x) { return 1.f / (1.f + expf(-x)); }
__device__ inline float bfbits2f(unsigned short u) {
    unsigned int x = ((unsigned int)u) << 16;
    float f; __builtin_memcpy(&f, &x, 4); return f;
}
__device__ inline short f2bf_bits(float f) {
    bf16 b = __float2bfloat16(f);
    short s; __builtin_memcpy(&s, &b, 2); return s;
}

// agent-scope coherent 8B accesses (compiler emits sc flags: write-through /
// cache-bypass so the Infinity Cache is the coherence point — NO bulk fences)
__device__ inline void g_store8(short* p, unsigned long long v) {
    __hip_atomic_store((unsigned long long*)p, v, __ATOMIC_RELAXED, __HIP_MEMORY_SCOPE_AGENT);
}
__device__ inline unsigned long long g_load8(const short* p) {
    return __hip_atomic_load((const unsigned long long*)p, __ATOMIC_RELAXED, __HIP_MEMORY_SCOPE_AGENT);
}

// ---------------------------------------------------------------------------
// MFMA GEMM: C(MxN) = A(MxK) @ B^T where A is (Mpad x lda) bf16 K-contiguous,
// B is (Npad x ldb) bf16 K-contiguous. K multiple of 32, pads zero-filled.
// EPI: 0 plain, 3 elu, 4 tanh
// ---------------------------------------------------------------------------
template <int EPI, typename CT>
__global__ __launch_bounds__(256) void gemm_mfma(
    const bf16* __restrict__ A, const bf16* __restrict__ B, CT* __restrict__ C,
    int M, int N, int K, int lda, int ldb, int ldc,
    long sAz, long sBz, long sCz,
    const bf16* __restrict__ P, long sPz, const float* __restrict__ bias, long sbz)
{
    const short* Ag = (const short*)A + (size_t)blockIdx.z * sAz;
    const short* Bg = (const short*)B + (size_t)blockIdx.z * sBz;
    CT* Cg = C + (size_t)blockIdx.z * sCz;
    (void)P; (void)sPz; (void)bias; (void)sbz;

    __shared__ short As[128 * 40];   // row stride 40 (80B) -> 2-way aliasing (free)
    __shared__ short Bs[128 * 40];
    int tid = threadIdx.x;
    int row0 = blockIdx.y * 128, col0 = blockIdx.x * 128;
    int wave = tid >> 6, lane = tid & 63;
    int wr = (wave >> 1) * 64, wc = (wave & 1) * 64;
    int lrow = lane & 15, lq = lane >> 4;

    f32x4 acc[4][4];
#pragma unroll
    for (int i = 0; i < 4; ++i)
#pragma unroll
        for (int j = 0; j < 4; ++j) acc[i][j] = (f32x4){0.f, 0.f, 0.f, 0.f};

    int sr = tid >> 2;
    int sc = (tid & 3) * 8;
    for (int k0 = 0; k0 < K; k0 += 32) {
        *(bf16x8*)&As[sr * 40 + sc]        = *(const bf16x8*)&Ag[(size_t)(row0 + sr) * lda + k0 + sc];
        *(bf16x8*)&As[(sr + 64) * 40 + sc] = *(const bf16x8*)&Ag[(size_t)(row0 + sr + 64) * lda + k0 + sc];
        *(bf16x8*)&Bs[sr * 40 + sc]        = *(const bf16x8*)&Bg[(size_t)(col0 + sr) * ldb + k0 + sc];
        *(bf16x8*)&Bs[(sr + 64) * 40 + sc] = *(const bf16x8*)&Bg[(size_t)(col0 + sr + 64) * ldb + k0 + sc];
        __syncthreads();
        bf16x8 aF[4], bF[4];
#pragma unroll
        for (int i = 0; i < 4; ++i) aF[i] = *(const bf16x8*)&As[(wr + i * 16 + lrow) * 40 + lq * 8];
#pragma unroll
        for (int j = 0; j < 4; ++j) bF[j] = *(const bf16x8*)&Bs[(wc + j * 16 + lrow) * 40 + lq * 8];
#pragma unroll
        for (int i = 0; i < 4; ++i)
#pragma unroll
            for (int j = 0; j < 4; ++j)
                acc[i][j] = __builtin_amdgcn_mfma_f32_16x16x32_bf16(aF[i], bF[j], acc[i][j], 0, 0, 0);
        __syncthreads();
    }
#pragma unroll
    for (int i = 0; i < 4; ++i) {
#pragma unroll
        for (int r = 0; r < 4; ++r) {
            int gm = row0 + wr + i * 16 + lq * 4 + r;
            if (gm >= M) continue;
#pragma unroll
            for (int j = 0; j < 4; ++j) {
                int gn = col0 + wc + j * 16 + lrow;
                if (gn >= N) continue;
                float v = acc[i][j][r];
                if constexpr (EPI == 3) v = v > 0.f ? v : (expf(v) - 1.f);
                if constexpr (EPI == 4) v = tanhf(v);
                storeC(&Cg[(size_t)gm * ldc + gn], v);
            }
        }
    }
}

// fp32 (R x Cc) row-major -> bf16 (Cpad x Rpad) transposed, zero-padded
__global__ void transpose_conv(const float* __restrict__ in, bf16* __restrict__ out,
                               int R, int Cc, int Rpad, int Cpad) {
    __shared__ float tile[32][33];
    int bc = blockIdx.x * 32, br = blockIdx.y * 32;
    int tx = threadIdx.x & 31, ty = threadIdx.x >> 5;
#pragma unroll
    for (int k = 0; k < 4; ++k) {
        int r = br + ty + 8 * k, c = bc + tx;
        tile[ty + 8 * k][tx] = (r < R && c < Cc) ? in[(size_t)r * Cc + c] : 0.f;
    }
    __syncthreads();
#pragma unroll
    for (int k = 0; k < 4; ++k) {
        int c = bc + ty + 8 * k, r = br + tx;
        if (c < Cpad && r < Rpad) out[(size_t)c * Rpad + r] = __float2bfloat16(tile[tx][ty + 8 * k]);
    }
}

// LSTM weight convert: rows permuted gate-interleaved: out row rp = j*4+q holds
// in row q*300+j. Out (1280 x Cpad) bf16, zero pads.
__global__ void convert_pad_perm(const float* __restrict__ in, bf16* __restrict__ out,
                                 int Cc, int Cpad) {
    int idx = blockIdx.x * 256 + threadIdx.x;
    if (idx >= kGp * Cpad) return;
    int rp = idx / Cpad, c = idx - rp * Cpad;
    int j = rp >> 2, q = rp & 3;
    float v = (j < kH && c < Cc) ? in[(size_t)(q * kH + j) * Cc + c] : 0.f;
    out[idx] = __float2bfloat16(v);
}

// permuted biases: b[dir][1280], b'[j*4+q] = b_orig[q*300+j], zero pads
__global__ void pack_biases_perm(const float* b0f, const float* b0b, const float* b1f,
                                 const float* b1b, float* b0, float* b1) {
    int i = blockIdx.x * 256 + threadIdx.x;
    if (i >= 2 * kGp) return;
    int dir = i / kGp, rp = i - dir * kGp;
    int j = rp >> 2, q = rp & 3;
    float v0 = 0.f, v1 = 0.f;
    if (j < kH) {
        v0 = dir ? b0b[q * kH + j] : b0f[q * kH + j];
        v1 = dir ? b1b[q * kH + j] : b1f[q * kH + j];
    }
    b0[i] = v0; b1[i] = v1;
}

// embedding gather -> xPad (kNLp x kKp0) bf16, zero pads
__global__ void gather_kernel(const int* __restrict__ tokens, const float* __restrict__ emb,
                              bf16* __restrict__ x) {
    int idx = blockIdx.x * 256 + threadIdx.x;
    if (idx >= kNLp * kKp0) return;
    int row = idx / kKp0, d = idx - row * kKp0;
    float v = 0.f;
    if (row < kNL && d < kD) {
        int l = row / kN, n = row - l * kN;
        v = emb[(size_t)tokens[n * kL + l] * kD + d];
    }
    x[idx] = __float2bfloat16(v);
}

// ---------------------------------------------------------------------------
// Persistent fused LSTM scan (one launch per layer).
// Grid = 60 blocks: cb(0..9) x rb(0..2) x dir(0..1), 1 block/CU.
// All cross-block h traffic uses agent-scope RELAXED atomics (8B) -> coherent
// at the Infinity Cache per-access; NO threadfence (no bulk L2 wb/inv).
// Barrier: per-thread vmcnt(0) drain -> syncthreads -> thread0 add+poll.
// ---------------------------------------------------------------------------
__device__ inline void group_barrier(int* bar, int target) {
    asm volatile("s_waitcnt vmcnt(0)" ::: "memory");  // own h stores at IF; own reads done (WAR)
    __syncthreads();
    if (threadIdx.x == 0) {
        __hip_atomic_fetch_add(bar, 1, __ATOMIC_RELAXED, __HIP_MEMORY_SCOPE_AGENT);
        while (__hip_atomic_load(bar, __ATOMIC_RELAXED, __HIP_MEMORY_SCOPE_AGENT) < target)
            __builtin_amdgcn_s_sleep(2);
    }
    __syncthreads();
}

template <bool WRITE_O0>
__global__ __launch_bounds__(256, 1) void lstm_scan_fused(
    const bf16* __restrict__ WhhP,   // [2][1280][320] bf16, gate-interleaved rows
    const bf16* __restrict__ P,      // [2][kNL][1200] bf16, gate-interleaved cols
    const float* __restrict__ biasP, // [2][1280] f32, gate-interleaved
    bf16* __restrict__ hst,          // [2 buf][2 dir][384][320] bf16, zeroed
    bf16* __restrict__ o0,           // [kNLp][608] bf16 (layer-0 only)
    int* __restrict__ bars)          // [6] ints, zeroed
{
    __shared__ short Bs[10][128][32];        // 80 KiB, k-group XOR-swizzled
    __shared__ float Gs[4 * 32 * 128];       // 64 KiB, row XOR-swizzled

    const int tid = threadIdx.x;
    const int bx  = blockIdx.x;
    const int cb  = bx % 10;
    const int rb  = (bx / 10) % 3;
    const int dir = bx / 30;
    int* bar = bars + dir * 3 + rb;

    const int wave = tid >> 6, lane = tid & 63;
    const int wr = (wave >> 1) * 64, wc = (wave & 1) * 64;
    const int lrow = lane & 15, lq = lane >> 4;
    const int col0 = cb * 128, row0 = rb * 128;

    // ---- stage Whh tile -> LDS once (swizzle: k-group g stored at g^((row>>1)&3)) ----
    {
        const short* Bg = (const short*)WhhP + (size_t)dir * kGp * kKp0;
        int sr = tid >> 2;           // 0..63
        int g  = tid & 3;            // k-group within 32-chunk
#pragma unroll
        for (int ch = 0; ch < 10; ++ch) {
            *(bf16x8*)&Bs[ch][sr][(g ^ ((sr >> 1) & 3)) * 8] =
                *(const bf16x8*)&Bg[(size_t)(col0 + sr) * kKp0 + ch * 32 + g * 8];
            *(bf16x8*)&Bs[ch][sr + 64][(g ^ (((sr + 64) >> 1) & 3)) * 8] =
                *(const bf16x8*)&Bg[(size_t)(col0 + sr + 64) * kKp0 + ch * 32 + g * 8];
        }
    }

    // pointwise assignment: thread owns 4 rows x 4 hidden units
    const int jj0 = (tid >> 5) * 4;       // local hidden base 0..28
    const int pr0 = (tid & 31) * 4;       // local row base 0..124
    const int jg0 = cb * 32 + jj0;        // global hidden base (mult of 4; 300%4==0)
    const bool jok = jg0 < kH;

    float bias[4][4];                     // [m][q]
#pragma unroll
    for (int m = 0; m < 4; ++m) {
        f32x4 b4 = *(const f32x4*)&biasP[dir * kGp + col0 + (jj0 + m) * 4];
#pragma unroll
        for (int q = 0; q < 4; ++q) bias[m][q] = b4[q];
    }
    float cst[4][4];                      // [m][rr] fp32 cell state
#pragma unroll
    for (int m = 0; m < 4; ++m)
#pragma unroll
        for (int r = 0; r < 4; ++r) cst[m][r] = 0.f;

    short* o0s = (short*)o0;

    // P[t] register prefetch (issued one step ahead; HBM latency hides under barrier)
    bf16x4 pv[4][4];                      // [m][rr]
    auto prefetchP = [&](int t) {
        const int teff = dir ? (kL - 1 - t) : t;
        const short* Pt = (const short*)P + (size_t)dir * kNL * kG + (size_t)teff * kN * kG;
        if (jok) {
#pragma unroll
            for (int m = 0; m < 4; ++m)
#pragma unroll
                for (int rr = 0; rr < 4; ++rr) {
                    int rg = row0 + pr0 + rr;
                    if (rg < kN)
                        pv[m][rr] = *(const bf16x4*)&Pt[(size_t)rg * kG + (size_t)(jg0 + m) * 4];
                }
        }
    };
    prefetchP(0);
    __syncthreads();

#pragma unroll 1
    for (int t = 0; t < kL; ++t) {
        const short* hr = (const short*)hst + ((size_t)(t & 1) * 2 + dir) * (kHB * kKp0);
        short* hw = (short*)hst + ((size_t)((t + 1) & 1) * 2 + dir) * (kHB * kKp0);
        const int teff = dir ? (kL - 1 - t) : t;

        // ---- GEMM: g += h_prev @ WhhP^T (A via agent-scope coherent loads, B from LDS) ----
        f32x4 acc[4][4];
#pragma unroll
        for (int i = 0; i < 4; ++i)
#pragma unroll
            for (int j = 0; j < 4; ++j) acc[i][j] = (f32x4){0.f, 0.f, 0.f, 0.f};

#pragma unroll
        for (int ch = 0; ch < 10; ++ch) {
            bf16x8 aF[4], bF[4];
#pragma unroll
            for (int i = 0; i < 4; ++i) {
                const short* ap = &hr[(size_t)(row0 + wr + i * 16 + lrow) * kKp0 + ch * 32 + lq * 8];
                union { unsigned long long u[2]; bf16x8 v; } cv;
                cv.u[0] = g_load8(ap);
                cv.u[1] = g_load8(ap + 4);
                aF[i] = cv.v;
            }
#pragma unroll
            for (int j = 0; j < 4; ++j) {
                int brow = wc + j * 16 + lrow;
                bF[j] = *(const bf16x8*)&Bs[ch][brow][(lq ^ ((brow >> 1) & 3)) * 8];
            }
#pragma unroll
            for (int i = 0; i < 4; ++i)
#pragma unroll
                for (int j = 0; j < 4; ++j)
                    acc[i][j] = __builtin_amdgcn_mfma_f32_16x16x32_bf16(aF[i], bF[j], acc[i][j], 0, 0, 0);
        }

        // ---- acc -> Gs (re-shard MFMA layout -> pointwise layout) ----
#pragma unroll
        for (int i = 0; i < 4; ++i) {
            int r0 = wr + i * 16 + lq * 4;
#pragma unroll
            for (int j = 0; j < 4; ++j) {
                int c = wc + j * 16 + lrow;
                int q = c & 3, jj = c >> 2;
                *(f32x4*)&Gs[(q * 32 + jj) * 128 + (r0 ^ ((jj & 7) << 2))] = acc[i][j];
            }
        }
        __syncthreads();

        // ---- pointwise LSTM update ----
        if (jok) {
            float hval[4][4];             // [rr][m]
#pragma unroll
            for (int m = 0; m < 4; ++m) {
                int jjl = jj0 + m;
                int sw = (jjl & 7) << 2;
                f32x4 gi4 = *(const f32x4*)&Gs[(0 * 32 + jjl) * 128 + (pr0 ^ sw)];
                f32x4 gf4 = *(const f32x4*)&Gs[(1 * 32 + jjl) * 128 + (pr0 ^ sw)];
                f32x4 gg4 = *(const f32x4*)&Gs[(2 * 32 + jjl) * 128 + (pr0 ^ sw)];
                f32x4 go4 = *(const f32x4*)&Gs[(3 * 32 + jjl) * 128 + (pr0 ^ sw)];
#pragma unroll
                for (int rr = 0; rr < 4; ++rr) {
                    int rg = row0 + pr0 + rr;
                    if (rg >= kN) continue;
                    float iv = sigf(gi4[rr] + bfbits2f((unsigned short)pv[m][rr][0]) + bias[m][0]);
                    float fv = sigf(gf4[rr] + bfbits2f((unsigned short)pv[m][rr][1]) + bias[m][1]);
                    float gv = tanhf(gg4[rr] + bfbits2f((unsigned short)pv[m][rr][2]) + bias[m][2]);
                    float ov = sigf(go4[rr] + bfbits2f((unsigned short)pv[m][rr][3]) + bias[m][3]);
                    float cc = fv * cst[m][rr] + iv * gv;
                    cst[m][rr] = cc;
                    hval[rr][m] = ov * tanhf(cc);
                }
            }
#pragma unroll
            for (int rr = 0; rr < 4; ++rr) {
                int rg = row0 + pr0 + rr;
                if (rg >= kN) continue;
                union { bf16x4 v; unsigned long long u; } hv;
#pragma unroll
                for (int m = 0; m < 4; ++m) hv.v[m] = f2bf_bits(hval[rr][m]);
                g_store8(&hw[(size_t)rg * kKp0 + jg0], hv.u);   // coherent at IF
                if constexpr (WRITE_O0)
                    *(bf16x4*)&o0s[((size_t)teff * kN + rg) * kKp1 + dir * kH + jg0] = hv.v;
            }
        }

        // prefetch next P while others finish pointwise / during barrier wait
        if (t + 1 < kL) prefetchP(t + 1);

        group_barrier(bar, 10 * (t + 1));
    }
}

__global__ void concat_hs0(const bf16* __restrict__ hbf0, const bf16* __restrict__ hbf1,
                           float* __restrict__ hs0) {
    int idx = blockIdx.x * 256 + threadIdx.x;
    if (idx >= kN * kG) return;
    int r = idx / kG, c = idx - r * kG;
    float v;
    if (c < 300)       v = toF(hbf0[(size_t)r * kKp0 + c]);
    else if (c < 600)  v = toF(hbf0[(size_t)(kNp + r) * kKp0 + (c - 300)]);
    else if (c < 900)  v = toF(hbf1[(size_t)r * kKp0 + (c - 600)]);
    else               v = toF(hbf1[(size_t)(kNp + r) * kKp0 + (c - 900)]);
    hs0[idx] = v;
}

__global__ void colsum_kernel(const float* __restrict__ hs, float* __restrict__ sum_hx) {
    int c = blockIdx.x * 256 + threadIdx.x;
    if (c >= kG) return;
    float s = 0.f;
    for (int r = 1; r < kN; ++r) s += hs[(size_t)r * kG + c];
    sum_hx[c] = s;
}

__global__ void gate_rows(const float* __restrict__ hs, const float* __restrict__ gW,
                          const float* __restrict__ gU, const float* __restrict__ sum_hx,
                          bf16* __restrict__ hin) {
    __shared__ float red[256];
    int n = blockIdx.x, tid = threadIdx.x;
    for (int c = tid; c < kG; c += 256)
        hin[(size_t)n * 2400 + c] = __float2bfloat16(hs[(size_t)n * kG + c]);
    if (n == 0) {
        for (int c = tid; c < kG; c += 256)
            hin[1200 + c] = __float2bfloat16(hs[c]);
        return;
    }
    float dw = 0.f, du = 0.f;
    for (int c = tid; c < kG; c += 256) {
        dw += hs[(size_t)n * kG + c] * gW[c];
        du += hs[c] * gU[c];
    }
    red[tid] = dw; __syncthreads();
    for (int s = 128; s > 0; s >>= 1) { if (tid < s) red[tid] += red[tid + s]; __syncthreads(); }
    float sdw = red[0]; __syncthreads();
    red[tid] = du; __syncthreads();
    for (int s = 128; s > 0; s >>= 1) { if (tid < s) red[tid] += red[tid + s]; __syncthreads(); }
    float sdu = red[0]; __syncthreads();
    float gval = sigf(sdw + sdu);
    for (int c = tid; c < kG; c += 256) {
        float v = gval * sum_hx[c] + (1.f - gval) * (345.f * hs[c]);
        hin[(size_t)n * 2400 + 1200 + c] = __float2bfloat16(v);
    }
}

__global__ void gat_scores(const float* __restrict__ Wh, const float* __restrict__ a,
                           float* __restrict__ s1, float* __restrict__ s2) {
    __shared__ float red[256];
    int n = blockIdx.x, tid = threadIdx.x;
    float d1 = 0.f, d2 = 0.f;
    for (int c = tid; c < kG; c += 256) {
        float w = Wh[(size_t)n * kG + c];
        d1 += w * a[c];
        d2 += w * a[kG + c];
    }
    red[tid] = d1; __syncthreads();
    for (int s = 128; s > 0; s >>= 1) { if (tid < s) red[tid] += red[tid + s]; __syncthreads(); }
    if (tid == 0) s1[n] = red[0];
    __syncthreads();
    red[tid] = d2; __syncthreads();
    for (int s = 128; s > 0; s >>= 1) { if (tid < s) red[tid] += red[tid + s]; __syncthreads(); }
    if (tid == 0) s2[n] = red[0];
}

__global__ void gat_softmax(const float* __restrict__ s1, const float* __restrict__ s2,
                            const int* __restrict__ adj, bf16* __restrict__ att) {
    __shared__ float red[256];
    __shared__ float sh_m, sh_s;
    int i = blockIdx.x, tid = threadIdx.x;
    float s1i = s1[i];
    float m = -1e30f;
    for (int j = tid; j < kN; j += 256) {
        if (adj[i * kN + j] > 0) {
            float e = s1i + s2[j];
            e = e > 0.f ? e : 0.01f * e;
            m = fmaxf(m, e);
        }
    }
    red[tid] = m; __syncthreads();
    for (int s = 128; s > 0; s >>= 1) { if (tid < s) red[tid] = fmaxf(red[tid], red[tid + s]); __syncthreads(); }
    if (tid == 0) sh_m = red[0];
    __syncthreads();
    m = sh_m;
    float sum = 0.f;
    for (int j = tid; j < kN; j += 256) {
        if (adj[i * kN + j] > 0) {
            float e = s1i + s2[j];
            e = e > 0.f ? e : 0.01f * e;
            sum += expf(e - m);
        }
    }
    red[tid] = sum; __syncthreads();
    for (int s = 128; s > 0; s >>= 1) { if (tid < s) red[tid] += red[tid + s]; __syncthreads(); }
    if (tid == 0) sh_s = red[0];
    __syncthreads();
    float inv = sh_s > 0.f ? 1.f / sh_s : 0.f;
    for (int j = tid; j < kN; j += 256) {
        float v = 0.f;
        if (adj[i * kN + j] > 0) {
            float e = s1i + s2[j];
            e = e > 0.f ? e : 0.01f * e;
            v = expf(e - m) * inv;
        }
        att[(size_t)i * 352 + j] = __float2bfloat16(v);
    }
}

__global__ void build_cat4(const float* __restrict__ hs2, bf16* __restrict__ cat4) {
    int idx = blockIdx.x * 256 + threadIdx.x;
    if (idx >= kN * 4800) return;
    int r = idx / 4800, c = idx - r * 4800;
    int chunk = c / kG, cc = c - chunk * kG;
    float hc = hs2[cc];
    float hv = hs2[(size_t)r * kG + cc];
    float v = (chunk == 0) ? hc : (chunk == 1) ? hv : (chunk == 2) ? hc * hv : (hc - hv);
    cat4[idx] = __float2bfloat16(v);
}

__global__ void row_dot_tanh(const float* __restrict__ hc3, const float* __restrict__ FC2,
                             float* __restrict__ b_att) {
    __shared__ float red[256];
    int n = blockIdx.x, tid = threadIdx.x;
    float d = 0.f;
    for (int c = tid; c < 9600; c += 256) d += hc3[(size_t)n * 9600 + c] * FC2[c];
    red[tid] = d; __syncthreads();
    for (int s = 128; s > 0; s >>= 1) { if (tid < s) red[tid] += red[tid + s]; __syncthreads(); }
    if (tid == 0) b_att[n] = tanhf(red[0]);
}

__global__ void ea_kernel(const float* __restrict__ hs2, const float* __restrict__ b_att,
                          float* __restrict__ ea) {
    int c = blockIdx.x * 256 + threadIdx.x;
    if (c >= kG) return;
    float s = 0.f, w = 0.f;
    for (int r = 0; r < kN; ++r) {
        float v = hs2[(size_t)r * kG + c];
        s += v;
        w += b_att[r] * v;
    }
    ea[c] = s / (float)kN;
    ea[kG + c] = w;
}

__global__ void final_kernel(const float* __restrict__ ea, const float* __restrict__ Wlin,
                             const float* __restrict__ blin, float* __restrict__ out) {
    __shared__ float red[256];
    int tid = threadIdx.x;
    float l0 = 0.f, l1 = 0.f;
    for (int c = tid; c < 2400; c += 256) {
        float e = ea[c];
        l0 += e * Wlin[c];
        l1 += e * Wlin[2400 + c];
    }
    red[tid] = l0; __syncthreads();
    for (int s = 128; s > 0; s >>= 1) { if (tid < s) red[tid] += red[tid + s]; __syncthreads(); }
    l0 = red[0]; __syncthreads();
    red[tid] = l1; __syncthreads();
    for (int s = 128; s > 0; s >>= 1) { if (tid < s) red[tid] += red[tid + s]; __syncthreads(); }
    l1 = red[0];
    if (tid == 0) {
        l0 += blin[0];
        l1 += blin[1];
        float m = fmaxf(l0, l1);
        float e0 = expf(l0 - m), e1 = expf(l1 - m);
        float inv = 1.f / (e0 + e1);
        out[0] = e0 * inv;
        out[1] = e1 * inv;
    }
}

// ---------------------------------------------------------------------------
extern "C" void kernel_launch(void* const* d_in, const int* in_sizes, int n_in,
                              void* d_out, int out_size, void* d_ws, size_t ws_size,
                              hipStream_t stream) {
    const int*   tokens  = (const int*)d_in[0];
    const int*   adj     = (const int*)d_in[1];
    const float* emb     = (const float*)d_in[2];
    const float* Wih_l0f = (const float*)d_in[3];
    const float* Whh_l0f = (const float*)d_in[4];
    const float* b_l0f   = (const float*)d_in[5];
    const float* Wih_l0b = (const float*)d_in[6];
    const float* Whh_l0b = (const float*)d_in[7];
    const float* b_l0b   = (const float*)d_in[8];
    const float* Wih_l1f = (const float*)d_in[9];
    const float* Whh_l1f = (const float*)d_in[10];
    const float* b_l1f   = (const float*)d_in[11];
    const float* Wih_l1b = (const float*)d_in[12];
    const float* Whh_l1b = (const float*)d_in[13];
    const float* b_l1b   = (const float*)d_in[14];
    const float* W_gat   = (const float*)d_in[15];
    const float* a_gat   = (const float*)d_in[16];
    const float* gate_W  = (const float*)d_in[17];
    const float* gate_U  = (const float*)d_in[18];
    const float* FC1     = (const float*)d_in[19];
    const float* FC2     = (const float*)d_in[20];
    const float* Wlin    = (const float*)d_in[21];
    const float* blin    = (const float*)d_in[22];
    float* out = (float*)d_out;
    (void)in_sizes; (void)n_in; (void)out_size; (void)ws_size;

    char* base = (char*)d_ws;
    size_t off = 0;
    auto alloc = [&](size_t bytes) {
        size_t cur = off;
        off += (bytes + 255) & ~(size_t)255;
        return base + cur;
    };

    // Region A with phase overlays:
    //   phase 1: [xPad 11.1MB | P0 83MB]
    //   phase 2: [P1 83MB] (x,P0 dead)
    //   phase 3: [WgatT 6.1 | hin 1.8 | att 0.27] (P1 dead)
    //   phase 4: [FC1T 92.2MB] (GAT scratch dead)
    const size_t xPad_sz = (size_t)kNLp * kKp0 * 2;
    char* regA = alloc(94181120);
    bf16* xPad  = (bf16*)(regA);
    bf16* P0    = (bf16*)(regA + xPad_sz);
    bf16* P1    = (bf16*)(regA);
    bf16* WgatT = (bf16*)(regA);
    bf16* hin   = (bf16*)(regA + 6144000);
    bf16* att   = (bf16*)(regA + 7987200);
    bf16* FC1T  = (bf16*)(regA);
    const size_t gatScratch_sz = 8257536;

    // o0 region, later overlaid by hc3
    char* o0r   = alloc((size_t)kNLp * kKp1 * 2);
    bf16*  o0   = (bf16*)o0r;
    float* hc3  = (float*)o0r;

    // h-state ping-pong buffers (layer0, layer1) + group barriers; zeroed each call
    const size_t hst_sz = (size_t)2 * 2 * kHB * kKp0 * 2;   // 983,040
    char* hblk = alloc(hst_sz * 2 + 256);
    bf16* hstA = (bf16*)hblk;
    bf16* hstB = (bf16*)(hblk + hst_sz);
    int*  bars = (int*)(hblk + 2 * hst_sz);

    bf16* Wih0 = (bf16*)alloc((size_t)2 * kGp * kKp0 * 2);
    bf16* Wih1 = (bf16*)alloc((size_t)2 * kGp * kKp1 * 2);
    bf16* Whh0 = (bf16*)alloc((size_t)2 * kGp * kKp0 * 2);
    bf16* Whh1 = (bf16*)alloc((size_t)2 * kGp * kKp0 * 2);
    float* b0p = (float*)alloc(2 * kGp * 4);
    float* b1p = (float*)alloc(2 * kGp * 4);
    float* hsA = (float*)alloc((size_t)kN * kG * 4);
    float* hsB = (float*)alloc((size_t)kN * kG * 4);
    float* sum_hx = (float*)alloc(kG * 4);
    float* Wh  = (float*)alloc((size_t)kN * kG * 4);
    bf16*  WhT = (bf16*)alloc((size_t)kGp * 352 * 2);
    float* s1  = (float*)alloc(kN * 4);
    float* s2  = (float*)alloc(kN * 4);
    bf16*  cat4 = (bf16*)alloc((size_t)kNp * 4800 * 2);
    float* b_att = (float*)alloc(kN * 4);
    float* ea  = (float*)alloc(2400 * 4);

    // ---- init (ws is re-poisoned every call) ----
    hipMemsetAsync(hblk, 0, hst_sz * 2 + 256, stream);
    hipMemsetAsync(o0r, 0, (size_t)kNLp * kKp1 * 2, stream);
    hipMemsetAsync(cat4, 0, (size_t)kNp * 4800 * 2, stream);

    // ---- weight prep (gate-interleaved permutation for all LSTM weights) ----
    pack_biases_perm<<<10, 256, 0, stream>>>(b_l0f, b_l0b, b_l1f, b_l1b, b0p, b1p);
    int cpp0 = (kGp * kKp0 + 255) / 256;
    int cpp1 = (kGp * kKp1 + 255) / 256;
    convert_pad_perm<<<cpp0, 256, 0, stream>>>(Wih_l0f, Wih0,              kD,     kKp0);
    convert_pad_perm<<<cpp0, 256, 0, stream>>>(Wih_l0b, Wih0 + kGp * kKp0, kD,     kKp0);
    convert_pad_perm<<<cpp1, 256, 0, stream>>>(Wih_l1f, Wih1,              2 * kH, kKp1);
    convert_pad_perm<<<cpp1, 256, 0, stream>>>(Wih_l1b, Wih1 + kGp * kKp1, 2 * kH, kKp1);
    convert_pad_perm<<<cpp0, 256, 0, stream>>>(Whh_l0f, Whh0,              kH,     kKp0);
    convert_pad_perm<<<cpp0, 256, 0, stream>>>(Whh_l0b, Whh0 + kGp * kKp0, kH,     kKp0);
    convert_pad_perm<<<cpp0, 256, 0, stream>>>(Whh_l1f, Whh1,              kH,     kKp0);
    convert_pad_perm<<<cpp0, 256, 0, stream>>>(Whh_l1b, Whh1 + kGp * kKp0, kH,     kKp0);

    // ---- embedding gather ----
    gather_kernel<<<(kNLp * kKp0 + 255) / 256, 256, 0, stream>>>(tokens, emb, xPad);

    // ---- layer-0 input projections (z=dir), gate-interleaved P columns ----
    gemm_mfma<0, bf16><<<dim3(10, kNLp / 128, 2), 256, 0, stream>>>(
        xPad, Wih0, P0, kNL, kG, kKp0, kKp0, kKp0, kG,
        0, (long)kGp * kKp0, (long)kNL * kG, nullptr, 0, nullptr, 0);

    // ---- layer-0 scan: ONE persistent kernel ----
    lstm_scan_fused<true><<<60, 256, 0, stream>>>(Whh0, P0, b0p, hstA, o0, bars);

    // ---- layer-1 input projections (P1 overlays dead xPad/P0) ----
    gemm_mfma<0, bf16><<<dim3(10, kNLp / 128, 2), 256, 0, stream>>>(
        o0, Wih1, P1, kNL, kG, kKp1, kKp1, kKp1, kG,
        0, (long)kGp * kKp1, (long)kNL * kG, nullptr, 0, nullptr, 0);

    // ---- layer-1 scan ----
    lstm_scan_fused<false><<<60, 256, 0, stream>>>(Whh1, P1, b1p, hstB, nullptr, bars + 6);

    // ---- hs0 = [hf0, hb0, hf1, hb1] (final h lives in buf0 of each state) ----
    concat_hs0<<<(kN * kG + 255) / 256, 256, 0, stream>>>(hstA, hstB, hsA);

    // ---- GAT scratch (overlays dead P1); zero pads then fill WgatT ----
    hipMemsetAsync(regA, 0, gatScratch_sz, stream);
    transpose_conv<<<dim3(kGp / 32, 2400 / 32), 256, 0, stream>>>(W_gat, WgatT, 2400, kG, 2400, kGp);

    float* hsIn = hsA;
    float* hsOut = hsB;
    for (int it = 0; it < 2; ++it) {
        colsum_kernel<<<(kG + 255) / 256, 256, 0, stream>>>(hsIn, sum_hx);
        gate_rows<<<kN, 256, 0, stream>>>(hsIn, gate_W, gate_U, sum_hx, hin);
        gemm_mfma<0, float><<<dim3(10, 3, 1), 256, 0, stream>>>(
            hin, WgatT, Wh, kN, kG, 2400, 2400, 2400, kG,
            0, 0, 0, nullptr, 0, nullptr, 0);
        gat_scores<<<kN, 256, 0, stream>>>(Wh, a_gat, s1, s2);
        gat_softmax<<<kN, 256, 0, stream>>>(s1, s2, adj, att);
        transpose_conv<<<dim3(kGp / 32, 352 / 32), 256, 0, stream>>>(Wh, WhT, kN, kG, 352, kGp);
        gemm_mfma<3, float><<<dim3(10, 3, 1), 256, 0, stream>>>(
            att, WhT, hsOut, kN, kG, 352, 352, 352, kG,
            0, 0, 0, nullptr, 0, nullptr, 0);
        float* tmp = hsIn; hsIn = hsOut; hsOut = tmp;
    }

    // ---- head ----
    build_cat4<<<(kN * 4800 + 255) / 256, 256, 0, stream>>>(hsIn, cat4);
    transpose_conv<<<dim3(9600 / 32, 4800 / 32), 256, 0, stream>>>(FC1, FC1T, 4800, 9600, 4800, 9600);
    gemm_mfma<4, float><<<dim3(75, 3, 1), 256, 0, stream>>>(
        cat4, FC1T, hc3, kN, 9600, 4800, 4800, 4800, 9600,
        0, 0, 0, nullptr, 0, nullptr, 0);
    row_dot_tanh<<<kN, 256, 0, stream>>>(hc3, FC2, b_att);
    ea_kernel<<<(kG + 255) / 256, 256, 0, stream>>>(hsIn, b_att, ea);
    final_kernel<<<1, 256, 0, stream>>>(ea, Wlin, blin, out);
}